// Round 1
// baseline (227.175 us; speedup 1.0000x reference)
//
#include <hip/hip_runtime.h>

#pragma clang fp contract(off)

namespace {
constexpr int T_ = 1024;
constexpr int B_ = 32;
constexpr int F_ = 512;
constexpr int BF_ = B_ * F_;     // 16384
constexpr int TBF_ = T_ * BF_;   // 16777216
constexpr int NITER = 10;

struct AB { float A, B; };

// combine(left, right): (ar*al, ar*bl + br) -- exact order of the jax comb
__device__ __forceinline__ AB comb(AB l, AB r) {
  AB o;
  o.A = r.A * l.A;
  float t = r.A * l.B;
  o.B = t + r.B;
  return o;
}

__device__ __forceinline__ AB shfl_up_ab(AB v, int d) {
  AB o;
  o.A = __shfl_up(v.A, d, 64);
  o.B = __shfl_up(v.B, d, 64);
  return o;
}

__device__ __forceinline__ AB shfl_xor_ab(AB v, int m) {
  AB o;
  o.A = __shfl_xor(v.A, m, 64);
  o.B = __shfl_xor(v.B, m, 64);
  return o;
}
}  // namespace

__global__ __launch_bounds__(256) void deer_lif_kernel(
    const float* __restrict__ x, const float* __restrict__ v_init,
    float* __restrict__ out) {
  __shared__ float smem[4][1024];  // 16 KB: [column][t]

  const int tid = threadIdx.x;
  const int blk = blockIdx.x;      // 0..4095
  const int b  = blk >> 7;         // 128 f-tiles per batch row
  const int f0 = (blk & 127) << 2; // 4 consecutive f per block

  const float* xb = x + (long)b * F_ + f0;

  // ---- stage x (1024 t-rows x 4 cols) into LDS transposed ----
#pragma unroll
  for (int r = 0; r < 4; ++r) {
    const int t = tid + (r << 8);
    const float4 v = *reinterpret_cast<const float4*>(xb + (long)t * BF_);
    smem[0][t] = v.x;
    smem[1][t] = v.y;
    smem[2][t] = v.z;
    smem[3][t] = v.w;
  }
  __syncthreads();

  const int w = tid >> 6;    // wave id == column index within tile
  const int lane = tid & 63;
  const bool lz = (lane == 0);

  // lane l owns t = 16*l + j, j = 0..15
  float xr[16];
#pragma unroll
  for (int q = 0; q < 4; ++q) {
    const float4 v =
        *reinterpret_cast<const float4*>(&smem[w][(lane << 4) + (q << 2)]);
    xr[4 * q + 0] = v.x;
    xr[4 * q + 1] = v.y;
    xr[4 * q + 2] = v.z;
    xr[4 * q + 3] = v.w;
  }

  const float v0 = v_init[b * F_ + f0 + w];

  // ---- warmstart: 2 steps of continuous dynamics on lane 0, rest zeros ----
  float y[16];
#pragma unroll
  for (int j = 0; j < 16; ++j) y[j] = 0.0f;
  if (lz) {
    float d0 = xr[0] - v0;
    float h0 = v0 + d0 * 0.5f;
    float d1 = xr[1] - h0;
    float h1 = h0 + d1 * 0.5f;
    y[0] = h0;
    y[1] = h1;
  }

#pragma unroll 1
  for (int it = 0; it < NITER; ++it) {
    // ys[0] for this lane = previous lane's y[15] (prev iterate), lane0 -> v0
    const float tail = __shfl_up(y[15], 1, 64);
    const float ys0 = lz ? v0 : tail;

    // ---- elementwise: a[t] = -G, b[t] = rhs (reference op order, no fma) ----
    AB e0[16];
#pragma unroll
    for (int j = 0; j < 16; ++j) {
      const float ys = (j == 0) ? ys0 : y[j - 1];
      const float d = xr[j] - ys;
      const float h = ys + d * 0.5f;          // /TAU with TAU=2 is exact *0.5
      const float hc = fminf(fmaxf(h, -20.0f), 20.0f);
      const float z = 4.0f * (hc - 0.7f);     // ALPHA*(hc-VTH), *4 exact
      const float e = expf(-z);
      const float den = 1.0f + e;
      const float s = 1.0f / den;             // sigmoid
      const float s4 = 4.0f * s;              // exact
      const float oms = 1.0f - s;
      const float sg = s4 * oms;              // (ALPHA*s)*(1-s)
      const float inner = 1.0f - sg;          // sg*(1-VRESET)=sg exact
      const float G = -(0.5f * inner);        // decay=0.5, *0.5 exact
      const float a = -G;
      const float gy = G * ys;
      const float rhs = h + gy;
      e0[j].A = a;
      e0[j].B = rhs;
    }

    // ---- up-sweep, in-lane levels (1024->512->256->128->64) ----
    AB e1[8], e2[4], e3[2];
#pragma unroll
    for (int i = 0; i < 8; ++i) e1[i] = comb(e0[2 * i], e0[2 * i + 1]);
#pragma unroll
    for (int i = 0; i < 4; ++i) e2[i] = comb(e1[2 * i], e1[2 * i + 1]);
#pragma unroll
    for (int i = 0; i < 2; ++i) e3[i] = comb(e2[2 * i], e2[2 * i + 1]);

    // ---- up-sweep, cross-lane butterflies: R[k] = reduction of my 2^k-lane block ----
    AB R[7];
    R[0] = comb(e3[0], e3[1]);
#pragma unroll
    for (int k = 0; k < 6; ++k) {
      const AB p = shfl_xor_ab(R[k], 1 << k);
      const AB lft = comb(R[k], p);   // I am left sibling
      const AB rgt = comb(p, R[k]);   // I am right sibling
      R[k + 1] = (lane & (1 << k)) ? rgt : lft;
    }

    // ---- down-sweep, cross-lane: S = inclusive prefix through end of my 2^k block
    AB S = R[6];
#pragma unroll
    for (int k = 5; k >= 0; --k) {
      const AB P = shfl_up_ab(S, 2 << k);           // scanned of previous parent
      const AB ce = comb(P, R[k]);
      const AB ev = ((lane >> k) == 0) ? R[k] : ce; // global block 0: no comb
      S = ((lane >> k) & 1) ? S : ev;               // odd child keeps parent prefix
    }

    // PL = inclusive prefix through end of previous lane (garbage on lane0, guarded)
    const AB PL = shfl_up_ab(S, 1);

    // ---- down-sweep, in-lane levels ----
    AB s3[2], s2[4], s1[8];
    s3[0] = lz ? e3[0] : comb(PL, e3[0]);
    s3[1] = S;
    s2[0] = lz ? e2[0] : comb(PL, e2[0]);
    s2[1] = s3[0];
    s2[2] = comb(s3[0], e2[2]);
    s2[3] = s3[1];
#pragma unroll
    for (int i = 0; i < 8; ++i) {
      if (i == 0)
        s1[0] = lz ? e1[0] : comb(PL, e1[0]);
      else if (i & 1)
        s1[i] = s2[i >> 1];
      else
        s1[i] = comb(s2[(i >> 1) - 1], e1[i]);
    }
#pragma unroll
    for (int j = 0; j < 16; ++j) {
      AB sj;
      if (j == 0)
        sj = lz ? e0[0] : comb(PL, e0[0]);
      else if (j & 1)
        sj = s1[j >> 1];
      else
        sj = comb(s1[(j >> 1) - 1], e0[j]);
      const float t0 = sj.A * v0;  // A*y0 + B (y0==v_init; exact when 0)
      y[j] = t0 + sj.B;
    }
  }

  // ---- stage y back through LDS, emit spike + y with coalesced row stores ----
#pragma unroll
  for (int q = 0; q < 4; ++q) {
    float4 v;
    v.x = y[4 * q + 0];
    v.y = y[4 * q + 1];
    v.z = y[4 * q + 2];
    v.w = y[4 * q + 3];
    *reinterpret_cast<float4*>(&smem[w][(lane << 4) + (q << 2)]) = v;
  }
  __syncthreads();

  float* outs = out;          // spike
  float* outy = out + TBF_;   // y
  const long rb = (long)b * F_ + f0;
#pragma unroll
  for (int r = 0; r < 4; ++r) {
    const int t = tid + (r << 8);
    const float y0v = smem[0][t];
    const float y1v = smem[1][t];
    const float y2v = smem[2][t];
    const float y3v = smem[3][t];
    const float4 yv = make_float4(y0v, y1v, y2v, y3v);
    const float4 sv = make_float4(y0v >= 0.7f ? 1.0f : 0.0f,
                                  y1v >= 0.7f ? 1.0f : 0.0f,
                                  y2v >= 0.7f ? 1.0f : 0.0f,
                                  y3v >= 0.7f ? 1.0f : 0.0f);
    const long off = (long)t * BF_ + rb;
    *reinterpret_cast<float4*>(outy + off) = yv;
    *reinterpret_cast<float4*>(outs + off) = sv;
  }
}

extern "C" void kernel_launch(void* const* d_in, const int* in_sizes, int n_in,
                              void* d_out, int out_size, void* d_ws, size_t ws_size,
                              hipStream_t stream) {
  const float* x = (const float*)d_in[0];
  const float* v_init = (const float*)d_in[1];
  float* out = (float*)d_out;
  deer_lif_kernel<<<dim3(4096), dim3(256), 0, stream>>>(x, v_init, out);
}

// Round 2
// 96.555 us; speedup vs baseline: 2.3528x; 2.3528x over previous
//
#include <hip/hip_runtime.h>

#pragma clang fp contract(off)

namespace {
constexpr int T_ = 1024;
constexpr int B_ = 32;
constexpr int F_ = 512;
constexpr int BF_ = B_ * F_;             // 16384
constexpr long TBF_ = (long)T_ * BF_;    // 16777216
constexpr int NITER = 10;
constexpr int NTHR = 512;                // 8 waves, 1 column each

// LDS swizzle at float4-block granularity: bijective (key bits 3..5 untouched
// by the XOR on bits 0..2). Makes stride-64B ds_read_b128 conflict-free and
// keeps the scalar transpose writes 2-way (free).
__device__ __forceinline__ int sw_idx(int t) {
  const int b = t >> 2;
  return ((b ^ ((b >> 3) & 7)) << 2) | (t & 3);
}

struct AB { float A, B; };
// combine(left, right) of affine maps v -> A*v + B
__device__ __forceinline__ AB comb(AB l, AB r) {
  AB o;
  o.A = r.A * l.A;
  o.B = __builtin_fmaf(r.A, l.B, r.B);
  return o;
}
}  // namespace

__global__ __launch_bounds__(NTHR, 6) void deer_lif_kernel(
    const float* __restrict__ x, const float* __restrict__ v_init,
    float* __restrict__ out) {
  __shared__ float smem[8][1024];  // 32 KB: [column][swizzled t]

  // Bijective XCD swizzle: 2048 blocks, 8 XCDs, 256 contiguous work-ids each
  // -> adjacent f-tiles (sharing 64B lines) land on the same XCD L2.
  const int raw = blockIdx.x;
  const int blk = (raw & 7) * 256 + (raw >> 3);

  const int b  = blk >> 6;          // batch row (64 f-groups per row)
  const int f0 = (blk & 63) << 3;   // 8 consecutive f per block

  const int tid = threadIdx.x;
  const int r0 = tid >> 1;          // row within 256-row pass
  const int c0 = (tid & 1) << 2;    // which float4 of the 8-col row

  // ---- stage x: coalesced 32B/row reads, transpose into swizzled LDS ----
  const float* xb = x + (long)b * F_ + f0 + c0;
#pragma unroll
  for (int p = 0; p < 4; ++p) {
    const int t = r0 + (p << 8);
    const float4 v = *reinterpret_cast<const float4*>(xb + (long)t * BF_);
    const int ti = sw_idx(t);
    smem[c0 + 0][ti] = v.x;
    smem[c0 + 1][ti] = v.y;
    smem[c0 + 2][ti] = v.z;
    smem[c0 + 3][ti] = v.w;
  }
  __syncthreads();

  const int w = tid >> 6;           // wave id == column index
  const int lane = tid & 63;
  const bool lz = (lane == 0);
  const float* col = smem[w];
  const float v0 = v_init[b * F_ + f0 + w];

  // swizzled byte offsets of this lane's 4 float4 fragments (t = 16*lane..+15)
  int roff[4];
#pragma unroll
  for (int q = 0; q < 4; ++q) {
    const int bb = (lane << 2) + q;
    roff[q] = (bb ^ ((bb >> 3) & 7)) << 2;
  }

  // ---- warmstart: 2 steps of continuous dynamics on lane 0, rest zeros ----
  float y[16];
#pragma unroll
  for (int j = 0; j < 16; ++j) y[j] = 0.0f;
  if (lz) {
    const float x0 = col[0], x1 = col[1];   // sw_idx(0)=0, sw_idx(1)=1
    const float h0 = v0 + (x0 - v0) * 0.5f;
    const float h1 = h0 + (x1 - h0) * 0.5f;
    y[0] = h0;
    y[1] = h1;
  }

#pragma unroll 1
  for (int it = 0; it < NITER; ++it) {
    // ys for this lane's first element = prev lane's y[15] (prev iterate)
    const float tail = __shfl_up(y[15], 1, 64);
    float ys = lz ? v0 : tail;

    float xr[16];
#pragma unroll
    for (int q = 0; q < 4; ++q) {
      const float4 v = *reinterpret_cast<const float4*>(&col[roff[q]]);
      xr[4 * q + 0] = v.x;
      xr[4 * q + 1] = v.y;
      xr[4 * q + 2] = v.z;
      xr[4 * q + 3] = v.w;
    }

    // ---- elementwise coeffs + serial in-lane compose ----
    float a[16], rb[16];
    float cA, cB;
#pragma unroll
    for (int j = 0; j < 16; ++j) {
      const float d = xr[j] - ys;
      const float h = __builtin_fmaf(d, 0.5f, ys);     // exact: 0.5*d exact
      const float hc = fminf(fmaxf(h, -20.0f), 20.0f);
      // exp(-4*(hc-0.7)) = 2^((0.7-hc)*4*log2e)
      const float e = __builtin_amdgcn_exp2f((0.7f - hc) * 5.770780163555852f);
      const float s = __builtin_amdgcn_rcpf(1.0f + e);  // sigmoid
      const float p = s * (1.0f - s);
      const float aj = 0.5f - (p + p);                  // a = 0.5*(1-4s(1-s))
      const float rj = __builtin_fmaf(-aj, ys, h);      // rhs = h - a*ys
      a[j] = aj;
      rb[j] = rj;
      if (j == 0) { cA = aj; cB = rj; }
      else        { cA = cA * aj; cB = __builtin_fmaf(cB, aj, rj); }
      ys = y[j];  // next element's ys = prev iterate's y[j]
    }

    // ---- 6-step Hillis-Steele inclusive scan of composed affine maps ----
    AB S; S.A = cA; S.B = cB;
#pragma unroll
    for (int dd = 1; dd < 64; dd <<= 1) {
      AB P;
      P.A = __shfl_up(S.A, dd, 64);
      P.B = __shfl_up(S.B, dd, 64);
      const AB c = comb(P, S);
      S.A = (lane >= dd) ? c.A : S.A;
      S.B = (lane >= dd) ? c.B : S.B;
    }
    const float PA = __shfl_up(S.A, 1, 64);
    const float PB = __shfl_up(S.B, 1, 64);
    float carry = lz ? v0 : __builtin_fmaf(PA, v0, PB);

    // ---- serial in-lane apply ----
#pragma unroll
    for (int j = 0; j < 16; ++j) {
      carry = __builtin_fmaf(a[j], carry, rb[j]);
      y[j] = carry;
    }
  }

  // ---- stage y back (same swizzle; wave only touches its own column) ----
#pragma unroll
  for (int q = 0; q < 4; ++q) {
    float4 v;
    v.x = y[4 * q + 0];
    v.y = y[4 * q + 1];
    v.z = y[4 * q + 2];
    v.w = y[4 * q + 3];
    *reinterpret_cast<float4*>(&smem[w][roff[q]]) = v;
  }
  __syncthreads();

  // ---- emit spike + y with 32B/row coalesced stores ----
  float* outs = out;          // spike
  float* outy = out + TBF_;   // y
  const long cb = (long)b * F_ + f0 + c0;
#pragma unroll
  for (int p = 0; p < 4; ++p) {
    const int t = r0 + (p << 8);
    const int ti = sw_idx(t);
    float4 yv;
    yv.x = smem[c0 + 0][ti];
    yv.y = smem[c0 + 1][ti];
    yv.z = smem[c0 + 2][ti];
    yv.w = smem[c0 + 3][ti];
    const float4 sv = make_float4(yv.x >= 0.7f ? 1.0f : 0.0f,
                                  yv.y >= 0.7f ? 1.0f : 0.0f,
                                  yv.z >= 0.7f ? 1.0f : 0.0f,
                                  yv.w >= 0.7f ? 1.0f : 0.0f);
    const long off = (long)t * BF_ + cb;
    *reinterpret_cast<float4*>(outy + off) = yv;
    *reinterpret_cast<float4*>(outs + off) = sv;
  }
}

extern "C" void kernel_launch(void* const* d_in, const int* in_sizes, int n_in,
                              void* d_out, int out_size, void* d_ws, size_t ws_size,
                              hipStream_t stream) {
  const float* x = (const float*)d_in[0];
  const float* v_init = (const float*)d_in[1];
  float* out = (float*)d_out;
  deer_lif_kernel<<<dim3(2048), dim3(NTHR), 0, stream>>>(x, v_init, out);
}

// Round 3
// 81.502 us; speedup vs baseline: 2.7873x; 1.1847x over previous
//
#include <hip/hip_runtime.h>

#pragma clang fp contract(off)

namespace {
constexpr int T_ = 1024;
constexpr int B_ = 32;
constexpr int F_ = 512;
constexpr int BF_ = B_ * F_;             // 16384
constexpr long TBF_ = (long)T_ * BF_;    // 16777216
constexpr int NITER = 10;
constexpr int NTHR = 512;                // 8 waves, 1 column each

typedef float v2f __attribute__((ext_vector_type(2)));

// exp(-4*(hc-0.7)) = 2^(-hc*K + 0.7K)
constexpr float KLOG = 5.770780163555852f;   // 4*log2(e)
constexpr float CLOG = 4.0395461144890964f;  // 0.7*4*log2(e)

// LDS swizzle at float4-block granularity (bijective): stride-64B
// ds_read_b128 conflict-free, scalar transpose writes stay cheap.
__device__ __forceinline__ int sw_idx(int t) {
  const int b = t >> 2;
  return ((b ^ ((b >> 3) & 7)) << 2) | (t & 3);
}

struct AB { float A, B; };
// combine(left, right) of affine maps v -> A*v + B (jax comb order)
__device__ __forceinline__ AB comb(AB l, AB r) {
  AB o;
  o.A = r.A * l.A;
  o.B = __builtin_fmaf(r.A, l.B, r.B);
  return o;
}

template <int CTRL, int RM>
__device__ __forceinline__ float dppf(float oldv, float src) {
  return __builtin_bit_cast(
      float, __builtin_amdgcn_update_dpp(__builtin_bit_cast(int, oldv),
                                         __builtin_bit_cast(int, src), CTRL,
                                         RM, 0xf, false));
}

// one scan step: P = shifted S (identity where invalid/masked), S = comb(P,S)
template <int CTRL, int RM>
__device__ __forceinline__ AB scan_step(AB S) {
  AB P;
  P.A = dppf<CTRL, RM>(1.0f, S.A);
  P.B = dppf<CTRL, RM>(0.0f, S.B);
  return comb(P, S);
}
}  // namespace

__global__ __launch_bounds__(NTHR, 4) void deer_lif_kernel(
    const float* __restrict__ x, const float* __restrict__ v_init,
    float* __restrict__ out) {
  __shared__ float smem[8][1024];  // 32 KB: [column][swizzled t]

  // Bijective XCD swizzle: 2048 blocks = 8 XCDs x 256 contiguous ids.
  const int raw = blockIdx.x;
  const int blk = (raw & 7) * 256 + (raw >> 3);

  const int b  = blk >> 6;          // batch row (64 f-groups per row)
  const int f0 = (blk & 63) << 3;   // 8 consecutive f per block

  const int tid = threadIdx.x;
  const int r0 = tid >> 1;          // row within 256-row pass
  const int c0 = (tid & 1) << 2;    // which float4 of the 8-col row

  // ---- stage x: coalesced 32B/row reads, transpose into swizzled LDS ----
  const float* xb = x + (long)b * F_ + f0 + c0;
#pragma unroll
  for (int p = 0; p < 4; ++p) {
    const int t = r0 + (p << 8);
    const float4 v = *reinterpret_cast<const float4*>(xb + (long)t * BF_);
    const int ti = sw_idx(t);
    smem[c0 + 0][ti] = v.x;
    smem[c0 + 1][ti] = v.y;
    smem[c0 + 2][ti] = v.z;
    smem[c0 + 3][ti] = v.w;
  }
  __syncthreads();

  const int w = tid >> 6;           // wave id == column index
  const int lane = tid & 63;
  const bool lz = (lane == 0);
  const float* col = smem[w];
  const float v0 = v_init[b * F_ + f0 + w];

  // swizzled byte offsets of this lane's 4 float4 fragments (t = 16*lane..+15)
  int roff[4];
#pragma unroll
  for (int q = 0; q < 4; ++q) {
    const int bb = (lane << 2) + q;
    roff[q] = (bb ^ ((bb >> 3) & 7)) << 2;
  }

  // ---- x lives in registers for all 10 sweeps ----
  float xr[16];
#pragma unroll
  for (int q = 0; q < 4; ++q) {
    const float4 v = *reinterpret_cast<const float4*>(&col[roff[q]]);
    xr[4 * q + 0] = v.x;
    xr[4 * q + 1] = v.y;
    xr[4 * q + 2] = v.z;
    xr[4 * q + 3] = v.w;
  }

  // ---- warmstart: 2 steps of continuous dynamics on lane 0, rest zeros ----
  float y[16];
#pragma unroll
  for (int j = 0; j < 16; ++j) y[j] = 0.0f;
  if (lz) {
    const float h0 = v0 + (xr[0] - v0) * 0.5f;
    const float h1 = h0 + (xr[1] - h0) * 0.5f;
    y[0] = h0;
    y[1] = h1;
  }

  const v2f half2 = {0.5f, 0.5f};
  const v2f one2 = {1.0f, 1.0f};
  const v2f nk2 = {-KLOG, -KLOG};
  const v2f ck2 = {CLOG, CLOG};

#pragma unroll 1
  for (int it = 0; it < NITER; ++it) {
    // ys for this lane's first element = prev lane's y[15]; lane0 -> v0
    const float ys0 = dppf<0x138, 0xf>(v0, y[15]);  // WAVE_SHR1

    // ---- packed elementwise coeffs + serial in-lane compose ----
    v2f a2[8], r2[8];
    float cA, cB;
#pragma unroll
    for (int p = 0; p < 8; ++p) {
      const v2f xs = {xr[2 * p], xr[2 * p + 1]};
      const v2f ys = {(p == 0) ? ys0 : y[2 * p - 1], y[2 * p]};
      const v2f d = xs - ys;
      const v2f h = __builtin_elementwise_fma(d, half2, ys);  // exact *0.5
      v2f hc;
      hc.x = __builtin_amdgcn_fmed3f(h.x, -20.0f, 20.0f);
      hc.y = __builtin_amdgcn_fmed3f(h.y, -20.0f, 20.0f);
      const v2f z = __builtin_elementwise_fma(hc, nk2, ck2);
      v2f e;
      e.x = __builtin_amdgcn_exp2f(z.x);
      e.y = __builtin_amdgcn_exp2f(z.y);
      const v2f num = one2 - e;
      const v2f den = one2 + e;
      v2f rc;
      rc.x = __builtin_amdgcn_rcpf(den.x);
      rc.y = __builtin_amdgcn_rcpf(den.y);
      const v2f t = num * rc;          // (1-e)/(1+e) = 1-2s
      const v2f t2 = t * t;
      const v2f aj = t2 * half2;       // a = 0.5*(1-2s)^2 == 0.5-2s(1-s)
      const v2f rj = __builtin_elementwise_fma(-aj, ys, h);  // rhs = h - a*ys
      a2[p] = aj;
      r2[p] = rj;
      if (p == 0) { cA = aj.x; cB = rj.x; }
      else        { cA = cA * aj.x; cB = __builtin_fmaf(cB, aj.x, rj.x); }
      cA = cA * aj.y;
      cB = __builtin_fmaf(cB, aj.y, rj.y);
    }

    // ---- 64-lane inclusive affine scan, all-DPP (no LDS) ----
    AB S;
    S.A = cA;
    S.B = cB;
    S = scan_step<0x111, 0xf>(S);  // row_shr:1
    S = scan_step<0x112, 0xf>(S);  // row_shr:2
    S = scan_step<0x114, 0xf>(S);  // row_shr:4
    S = scan_step<0x118, 0xf>(S);  // row_shr:8
    S = scan_step<0x142, 0xa>(S);  // row_bcast:15 -> rows 1,3
    S = scan_step<0x143, 0xc>(S);  // row_bcast:31 -> rows 2,3

    // carry into this lane = value at end of previous lane (lane0 -> v0)
    const float cinc = __builtin_fmaf(S.A, v0, S.B);
    float carry = dppf<0x138, 0xf>(v0, cinc);  // WAVE_SHR1

    // ---- serial in-lane apply ----
#pragma unroll
    for (int j = 0; j < 16; ++j) {
      const float aj = (j & 1) ? a2[j >> 1].y : a2[j >> 1].x;
      const float rj = (j & 1) ? r2[j >> 1].y : r2[j >> 1].x;
      carry = __builtin_fmaf(aj, carry, rj);
      y[j] = carry;
    }
  }

  // ---- stage y back (same swizzle; wave only touches its own column) ----
#pragma unroll
  for (int q = 0; q < 4; ++q) {
    float4 v;
    v.x = y[4 * q + 0];
    v.y = y[4 * q + 1];
    v.z = y[4 * q + 2];
    v.w = y[4 * q + 3];
    *reinterpret_cast<float4*>(&smem[w][roff[q]]) = v;
  }
  __syncthreads();

  // ---- emit spike + y with 32B/row coalesced stores ----
  float* outs = out;          // spike
  float* outy = out + TBF_;   // y
  const long cb = (long)b * F_ + f0 + c0;
#pragma unroll
  for (int p = 0; p < 4; ++p) {
    const int t = r0 + (p << 8);
    const int ti = sw_idx(t);
    float4 yv;
    yv.x = smem[c0 + 0][ti];
    yv.y = smem[c0 + 1][ti];
    yv.z = smem[c0 + 2][ti];
    yv.w = smem[c0 + 3][ti];
    const float4 sv = make_float4(yv.x >= 0.7f ? 1.0f : 0.0f,
                                  yv.y >= 0.7f ? 1.0f : 0.0f,
                                  yv.z >= 0.7f ? 1.0f : 0.0f,
                                  yv.w >= 0.7f ? 1.0f : 0.0f);
    const long off = (long)t * BF_ + cb;
    *reinterpret_cast<float4*>(outy + off) = yv;
    *reinterpret_cast<float4*>(outs + off) = sv;
  }
}

extern "C" void kernel_launch(void* const* d_in, const int* in_sizes, int n_in,
                              void* d_out, int out_size, void* d_ws, size_t ws_size,
                              hipStream_t stream) {
  const float* x = (const float*)d_in[0];
  const float* v_init = (const float*)d_in[1];
  float* out = (float*)d_out;
  deer_lif_kernel<<<dim3(2048), dim3(NTHR), 0, stream>>>(x, v_init, out);
}

// Round 4
// 74.543 us; speedup vs baseline: 3.0475x; 1.0934x over previous
//
#include <hip/hip_runtime.h>

#pragma clang fp contract(off)

namespace {
constexpr int T_ = 1024;
constexpr int B_ = 32;
constexpr int F_ = 512;
constexpr int BF_ = B_ * F_;             // 16384
constexpr long TBF_ = (long)T_ * BF_;    // 16777216
constexpr int NITER = 10;
constexpr int NTHR = 256;                // 4 waves, 2 columns each

typedef float v2f __attribute__((ext_vector_type(2)));

// exp(-4*(hc-0.7)) = 2^(-hc*K + 0.7K)
constexpr float KLOG = 5.770780163555852f;   // 4*log2(e)
constexpr float CLOG = 4.0395461144890964f;  // 0.7*4*log2(e)

// bijective swizzle of 16B-block index (bits 3..5 XORed into 0..2):
// makes the stride-128B per-lane ds_read_b128 pattern conflict-free.
__device__ __forceinline__ int swz(int bb) { return bb ^ ((bb >> 3) & 7); }

struct ABp { v2f A, B; };
// combine(left, right) of affine maps v -> A*v + B (jax comb order), packed
__device__ __forceinline__ ABp combp(ABp l, ABp r) {
  ABp o;
  o.A = r.A * l.A;
  o.B = __builtin_elementwise_fma(r.A, l.B, r.B);
  return o;
}

template <int CTRL, int RM>
__device__ __forceinline__ float dppf(float oldv, float src) {
  return __builtin_bit_cast(
      float, __builtin_amdgcn_update_dpp(__builtin_bit_cast(int, oldv),
                                         __builtin_bit_cast(int, src), CTRL,
                                         RM, 0xf, false));
}

// one scan step: P = shifted S (identity where invalid/masked), S = comb(P,S)
template <int CTRL, int RM>
__device__ __forceinline__ ABp scan_step(ABp S) {
  ABp P;
  P.A.x = dppf<CTRL, RM>(1.0f, S.A.x);
  P.A.y = dppf<CTRL, RM>(1.0f, S.A.y);
  P.B.x = dppf<CTRL, RM>(0.0f, S.B.x);
  P.B.y = dppf<CTRL, RM>(0.0f, S.B.y);
  return combp(P, S);
}
}  // namespace

__global__ __launch_bounds__(NTHR, 3) void deer_lif_kernel(
    const float* __restrict__ x, const float* __restrict__ v_init,
    float* __restrict__ out) {
  // 32 KB, flat floats: per wave an 8 KB region of 512 16B blocks; block
  // bb = t>>1 holds (x[t],x[t+1]) x (col even, col odd), swizzled by swz().
  __shared__ float smem[8192];

  // Bijective XCD swizzle: 2048 blocks = 8 XCDs x 256 contiguous ids.
  const int raw = blockIdx.x;
  const int blk = (raw & 7) * 256 + (raw >> 3);

  const int b  = blk >> 6;          // batch row (64 f-groups per row)
  const int f0 = (blk & 63) << 3;   // 8 consecutive f per block

  const int tid = threadIdx.x;
  const int rt = tid >> 1;          // row within 128-row pass
  const int c0 = (tid & 1) << 2;    // which float4 of the 8-col row
  const int wr0 = c0 >> 1;          // first wave-region this thread feeds

  // ---- stage x: coalesced 32B/row reads, transpose into swizzled LDS ----
  const float* xb = x + (long)b * F_ + f0 + c0;
#pragma unroll
  for (int p = 0; p < 8; ++p) {
    const int t = rt + (p << 7);
    const float4 v = *reinterpret_cast<const float4*>(xb + (long)t * BF_);
    const int base = (swz(t >> 1) << 2) + ((t & 1) << 1);
    float2 lo, hi;
    lo.x = v.x; lo.y = v.y;
    hi.x = v.z; hi.y = v.w;
    *reinterpret_cast<float2*>(&smem[wr0 * 2048 + base]) = lo;
    *reinterpret_cast<float2*>(&smem[(wr0 + 1) * 2048 + base]) = hi;
  }
  __syncthreads();

  const int w = tid >> 6;           // wave id; owns columns 2w, 2w+1
  const int lane = tid & 63;
  const bool lz = (lane == 0);

  v2f v0;
  v0.x = v_init[b * F_ + f0 + 2 * w];
  v0.y = v_init[b * F_ + f0 + 2 * w + 1];

  // ---- x lives in registers for all 10 sweeps (packed over 2 columns) ----
  v2f xp[16];
#pragma unroll
  for (int q = 0; q < 8; ++q) {
    const int bbs = swz((lane << 3) + q);
    const float4 v =
        *reinterpret_cast<const float4*>(&smem[w * 2048 + (bbs << 2)]);
    xp[2 * q].x = v.x;
    xp[2 * q].y = v.y;
    xp[2 * q + 1].x = v.z;
    xp[2 * q + 1].y = v.w;
  }

  // ---- warmstart: 2 steps of continuous dynamics on lane 0, rest zeros ----
  v2f y[16];
#pragma unroll
  for (int j = 0; j < 16; ++j) y[j] = (v2f){0.0f, 0.0f};
  if (lz) {
    const v2f h0 = v0 + (xp[0] - v0) * 0.5f;
    const v2f h1 = h0 + (xp[1] - h0) * 0.5f;
    y[0] = h0;
    y[1] = h1;
  }

  const v2f half2 = {0.5f, 0.5f};
  const v2f one2 = {1.0f, 1.0f};
  const v2f nk2 = {-KLOG, -KLOG};
  const v2f ck2 = {CLOG, CLOG};
  const v2f lo2 = {-20.0f, -20.0f};

#pragma unroll 1
  for (int it = 0; it < NITER; ++it) {
    // ys for this lane's first element = prev lane's y[15]; lane0 -> v0
    v2f ys0;
    ys0.x = dppf<0x138, 0xf>(v0.x, y[15].x);  // WAVE_SHR1
    ys0.y = dppf<0x138, 0xf>(v0.y, y[15].y);

    // ---- packed elementwise coeffs + serial packed compose ----
    v2f a[16], r[16];
    v2f cA, cB;
#pragma unroll
    for (int j = 0; j < 16; ++j) {
      const v2f ys = (j == 0) ? ys0 : y[j - 1];
      const v2f d = xp[j] - ys;
      const v2f h = __builtin_elementwise_fma(d, half2, ys);  // exact *0.5
      // lower clamp only: for h>20 the algebra saturates to a=0.5 exactly,
      // matching the reference's clip (rhs uses unclamped h either way).
      const v2f hc = __builtin_elementwise_max(h, lo2);
      const v2f z = __builtin_elementwise_fma(hc, nk2, ck2);
      v2f e;
      e.x = __builtin_amdgcn_exp2f(z.x);
      e.y = __builtin_amdgcn_exp2f(z.y);
      const v2f num = one2 - e;
      const v2f den = one2 + e;
      v2f rc;
      rc.x = __builtin_amdgcn_rcpf(den.x);
      rc.y = __builtin_amdgcn_rcpf(den.y);
      const v2f t = num * rc;          // (1-e)/(1+e) = 1-2s
      const v2f t2 = t * t;
      const v2f aj = t2 * half2;       // a = 0.5*(1-2s)^2 == 0.5-2s(1-s)
      const v2f rj = __builtin_elementwise_fma(-aj, ys, h);  // rhs = h - a*ys
      a[j] = aj;
      r[j] = rj;
      if (j == 0) {
        cA = aj;
        cB = rj;
      } else {
        cA = cA * aj;
        cB = __builtin_elementwise_fma(cB, aj, rj);
      }
    }

    // ---- 64-lane inclusive affine scan, all-DPP, packed over 2 cols ----
    ABp S;
    S.A = cA;
    S.B = cB;
    S = scan_step<0x111, 0xf>(S);  // row_shr:1
    S = scan_step<0x112, 0xf>(S);  // row_shr:2
    S = scan_step<0x114, 0xf>(S);  // row_shr:4
    S = scan_step<0x118, 0xf>(S);  // row_shr:8
    S = scan_step<0x142, 0xa>(S);  // row_bcast:15 -> rows 1,3
    S = scan_step<0x143, 0xc>(S);  // row_bcast:31 -> rows 2,3

    // carry into this lane = value at end of previous lane (lane0 -> v0)
    const v2f cinc = __builtin_elementwise_fma(S.A, v0, S.B);
    v2f carry;
    carry.x = dppf<0x138, 0xf>(v0.x, cinc.x);  // WAVE_SHR1
    carry.y = dppf<0x138, 0xf>(v0.y, cinc.y);

    // ---- serial packed apply ----
#pragma unroll
    for (int j = 0; j < 16; ++j) {
      carry = __builtin_elementwise_fma(a[j], carry, r[j]);
      y[j] = carry;
    }
  }

  // ---- stage y back (same swizzle; wave only touches its own region) ----
#pragma unroll
  for (int q = 0; q < 8; ++q) {
    const int bbs = swz((lane << 3) + q);
    float4 v;
    v.x = y[2 * q].x;
    v.y = y[2 * q].y;
    v.z = y[2 * q + 1].x;
    v.w = y[2 * q + 1].y;
    *reinterpret_cast<float4*>(&smem[w * 2048 + (bbs << 2)]) = v;
  }
  __syncthreads();

  // ---- emit spike + y with 32B/row coalesced stores ----
  float* outs = out;          // spike
  float* outy = out + TBF_;   // y
  const long cb = (long)b * F_ + f0 + c0;
#pragma unroll
  for (int p = 0; p < 8; ++p) {
    const int t = rt + (p << 7);
    const int base = (swz(t >> 1) << 2) + ((t & 1) << 1);
    const float2 lo = *reinterpret_cast<const float2*>(&smem[wr0 * 2048 + base]);
    const float2 hi =
        *reinterpret_cast<const float2*>(&smem[(wr0 + 1) * 2048 + base]);
    const float4 yv = make_float4(lo.x, lo.y, hi.x, hi.y);
    const float4 sv = make_float4(yv.x >= 0.7f ? 1.0f : 0.0f,
                                  yv.y >= 0.7f ? 1.0f : 0.0f,
                                  yv.z >= 0.7f ? 1.0f : 0.0f,
                                  yv.w >= 0.7f ? 1.0f : 0.0f);
    const long off = (long)t * BF_ + cb;
    *reinterpret_cast<float4*>(outy + off) = yv;
    *reinterpret_cast<float4*>(outs + off) = sv;
  }
}

extern "C" void kernel_launch(void* const* d_in, const int* in_sizes, int n_in,
                              void* d_out, int out_size, void* d_ws, size_t ws_size,
                              hipStream_t stream) {
  const float* x = (const float*)d_in[0];
  const float* v_init = (const float*)d_in[1];
  float* out = (float*)d_out;
  deer_lif_kernel<<<dim3(2048), dim3(NTHR), 0, stream>>>(x, v_init, out);
}